// Round 7
// baseline (811.411 us; speedup 1.0000x reference)
//
#include <hip/hip_runtime.h>
#include <math.h>

typedef __attribute__((ext_vector_type(8))) short short8;
typedef __attribute__((ext_vector_type(16))) float floatx16;

__device__ __forceinline__ float silu_f(float v) { return v / (1.0f + expf(-v)); }
__device__ __forceinline__ float bf2f(unsigned short u) {
    unsigned int x = ((unsigned int)u) << 16;
    return __uint_as_float(x);
}
__device__ __forceinline__ unsigned short f2bf(float f) {
    unsigned int u = __float_as_uint(f);
    u += 0x7FFFu + ((u >> 16) & 1u);
    return (unsigned short)(u >> 16);
}

struct BSlots { const unsigned short* p[4]; };

// ---------------- bf16 MFMA GEMM (1x1 conv), single-barrier double-buffered.
// 128x256 tile, 256 threads (4 waves as 2m x 2n). Per K-step:
//   compute buf[cur] -> stage regs->buf[cur^1] -> issue loads k+2 -> barrier.
// One barrier per K-step (writes go to the buffer nobody reads this iter);
// reg-staging means the barrier only drains lgkmcnt -- prefetched global
// loads stay in flight across it. MFMA cluster starts right after barrier.
// out[(z*OC+m)*4096+n] = EPI( sum_k (Ah+Al)[m][k] * B[k][n] + bias[m] )
// Dual-branch: if Ahp2 != null and m0>=512, use (Ahp2,Alp2,bias2,bs2) with
// branch-local row mA = m0-512 (merged cv1/cv2 dispatch).
// EPI: 0 = SiLU -> bf16; 1 = gate-mult by Y2b -> bf16; 2 = SiLU -> f32
#define APITCH 36   // bf16 elems per A LDS row (32 data + 4 pad)
#define BPITCH 18   // dwords per B LDS row (16 data + 2 pad), k-pairs per dword

template <int EPI>
__global__ __launch_bounds__(256, 2)
void gemm_mfma(const unsigned short* __restrict__ Ahp,
               const unsigned short* __restrict__ Alp,
               const unsigned short* __restrict__ Ahp2,
               const unsigned short* __restrict__ Alp2, int ldK,
               BSlots bs, BSlots bs2, long bstride,
               const float* __restrict__ bias, const float* __restrict__ bias2,
               void* __restrict__ outv, int OC,
               const unsigned short* __restrict__ gate, int b0, int K)
{
    __shared__ __align__(16) unsigned short As[2][2][128 * APITCH];  // [buf][hi/lo]
    __shared__ __align__(16) unsigned int   Bsm[2][256 * BPITCH];    // [buf]

    const int t  = threadIdx.x;
    const int z  = blockIdx.z;
    const int m0 = blockIdx.y * 128;
    const int n0 = blockIdx.x * 256;

    int mA = m0;
    if (Ahp2 != nullptr && m0 >= 512) {
        Ahp = Ahp2; Alp = Alp2; bias = bias2; bs = bs2; mA = m0 - 512;
    }

    // staging ids
    const int am = t >> 1, ahf = t & 1;          // A: row, k-half (16 elems)
    const int bkg = t & 7, bn8 = t >> 3;         // B: k-group (4 rows), n-octet

    // compute ids
    const int w = t >> 6, lane = t & 63;
    const int wm = (w & 1) * 64, wn = (w >> 1) * 128;
    const int lm = lane & 31, q = lane >> 5;

    floatx16 acc[2][4];
#pragma unroll
    for (int i = 0; i < 2; ++i)
#pragma unroll
        for (int j = 0; j < 4; ++j)
#pragma unroll
            for (int r = 0; r < 16; ++r) acc[i][j][r] = 0.0f;

    const unsigned short* Aph = Ahp + (size_t)(mA + am) * ldK + ahf * 16;
    const unsigned short* Apl = Alp + (size_t)(mA + am) * ldK + ahf * 16;

    uint4 ah0, ah1, al0, al1, r0, r1, r2, r3;

    // ---- prologue: load tile 0, stage into buf 0, prefetch tile 1
    {
        ah0 = *(const uint4*)(Aph);
        ah1 = *(const uint4*)(Aph + 8);
        al0 = *(const uint4*)(Apl);
        al1 = *(const uint4*)(Apl + 8);
        const unsigned short* Bp = bs.p[0] + (size_t)z * bstride
                                 + (size_t)(bkg * 4) * 4096 + n0 + bn8 * 8;
        r0 = *(const uint4*)(Bp);
        r1 = *(const uint4*)(Bp + 4096);
        r2 = *(const uint4*)(Bp + 8192);
        r3 = *(const uint4*)(Bp + 12288);
    }
    {
        unsigned short* Ad0 = &As[0][0][am * APITCH + ahf * 16];
        unsigned short* Ad1 = &As[0][1][am * APITCH + ahf * 16];
        ((uint2*)Ad0)[0] = *((const uint2*)&ah0);
        ((uint2*)Ad0)[1] = *((const uint2*)&ah0 + 1);
        ((uint2*)Ad0)[2] = *((const uint2*)&ah1);
        ((uint2*)Ad0)[3] = *((const uint2*)&ah1 + 1);
        ((uint2*)Ad1)[0] = *((const uint2*)&al0);
        ((uint2*)Ad1)[1] = *((const uint2*)&al0 + 1);
        ((uint2*)Ad1)[2] = *((const uint2*)&al1);
        ((uint2*)Ad1)[3] = *((const uint2*)&al1 + 1);
        const unsigned int* d0 = (const unsigned int*)&r0;
        const unsigned int* d1 = (const unsigned int*)&r1;
        const unsigned int* d2 = (const unsigned int*)&r2;
        const unsigned int* d3 = (const unsigned int*)&r3;
#pragma unroll
        for (int i = 0; i < 8; ++i) {
            unsigned int sel = (i & 1) ? 0x07060302u : 0x05040100u;
            uint2 pv;
            pv.x = __builtin_amdgcn_perm(d1[i >> 1], d0[i >> 1], sel);
            pv.y = __builtin_amdgcn_perm(d3[i >> 1], d2[i >> 1], sel);
            *(uint2*)&Bsm[0][(bn8 * 8 + i) * BPITCH + bkg * 2] = pv;
        }
    }
    if (32 < K) {
        ah0 = *(const uint4*)(Aph + 32);
        ah1 = *(const uint4*)(Aph + 40);
        al0 = *(const uint4*)(Apl + 32);
        al1 = *(const uint4*)(Apl + 40);
        const unsigned short* Bp = bs.p[0] + (size_t)z * bstride
                                 + (size_t)(32 + bkg * 4) * 4096 + n0 + bn8 * 8;
        r0 = *(const uint4*)(Bp);
        r1 = *(const uint4*)(Bp + 4096);
        r2 = *(const uint4*)(Bp + 8192);
        r3 = *(const uint4*)(Bp + 12288);
    }
    __syncthreads();

    int cur = 0;
    for (int k0 = 0; k0 < K; k0 += 32) {
        // ---- compute from buf[cur]: 2 k-steps x (2m x 4n) x (hi+lo)
        const unsigned short* A0 = &As[cur][0][0];
        const unsigned short* A1 = &As[cur][1][0];
        const unsigned int*   Bc = &Bsm[cur][0];
        __builtin_amdgcn_s_setprio(1);
#pragma unroll
        for (int s = 0; s < 2; ++s) {
            union { short8 v; uint2 u[2]; } afh[2], afl[2], bfr[4];
#pragma unroll
            for (int i = 0; i < 2; ++i) {
                int rb = (wm + 32 * i + lm) * APITCH + s * 16 + q * 8;
                afh[i].u[0] = *(const uint2*)&A0[rb];
                afh[i].u[1] = *(const uint2*)&A0[rb + 4];
                afl[i].u[0] = *(const uint2*)&A1[rb];
                afl[i].u[1] = *(const uint2*)&A1[rb + 4];
            }
#pragma unroll
            for (int j = 0; j < 4; ++j) {
                int nb = (wn + 32 * j + lm) * BPITCH + s * 8 + q * 4;
                bfr[j].u[0] = *(const uint2*)&Bc[nb];
                bfr[j].u[1] = *(const uint2*)&Bc[nb + 2];
            }
#pragma unroll
            for (int i = 0; i < 2; ++i)
#pragma unroll
                for (int j = 0; j < 4; ++j) {
                    acc[i][j] = __builtin_amdgcn_mfma_f32_32x32x16_bf16(
                        afh[i].v, bfr[j].v, acc[i][j], 0, 0, 0);
                    acc[i][j] = __builtin_amdgcn_mfma_f32_32x32x16_bf16(
                        afl[i].v, bfr[j].v, acc[i][j], 0, 0, 0);
                }
        }
        __builtin_amdgcn_s_setprio(0);

        // ---- stage tile k0+32 into buf[cur^1] (regs prefetched last iter)
        const int k1 = k0 + 32;
        if (k1 < K) {
            const int nxt = cur ^ 1;
            unsigned short* Ad0 = &As[nxt][0][am * APITCH + ahf * 16];
            unsigned short* Ad1 = &As[nxt][1][am * APITCH + ahf * 16];
            ((uint2*)Ad0)[0] = *((const uint2*)&ah0);
            ((uint2*)Ad0)[1] = *((const uint2*)&ah0 + 1);
            ((uint2*)Ad0)[2] = *((const uint2*)&ah1);
            ((uint2*)Ad0)[3] = *((const uint2*)&ah1 + 1);
            ((uint2*)Ad1)[0] = *((const uint2*)&al0);
            ((uint2*)Ad1)[1] = *((const uint2*)&al0 + 1);
            ((uint2*)Ad1)[2] = *((const uint2*)&al1);
            ((uint2*)Ad1)[3] = *((const uint2*)&al1 + 1);
            const unsigned int* d0 = (const unsigned int*)&r0;
            const unsigned int* d1 = (const unsigned int*)&r1;
            const unsigned int* d2 = (const unsigned int*)&r2;
            const unsigned int* d3 = (const unsigned int*)&r3;
#pragma unroll
            for (int i = 0; i < 8; ++i) {
                unsigned int sel = (i & 1) ? 0x07060302u : 0x05040100u;
                uint2 pv;
                pv.x = __builtin_amdgcn_perm(d1[i >> 1], d0[i >> 1], sel);
                pv.y = __builtin_amdgcn_perm(d3[i >> 1], d2[i >> 1], sel);
                *(uint2*)&Bsm[nxt][(bn8 * 8 + i) * BPITCH + bkg * 2] = pv;
            }
            // ---- issue prefetch for tile k0+64 (regs now free)
            const int k2 = k0 + 64;
            if (k2 < K) {
                ah0 = *(const uint4*)(Aph + k2);
                ah1 = *(const uint4*)(Aph + k2 + 8);
                al0 = *(const uint4*)(Apl + k2);
                al1 = *(const uint4*)(Apl + k2 + 8);
                const unsigned short* Bp = bs.p[k2 >> 8] + (size_t)z * bstride
                                         + (size_t)((k2 & 255) + bkg * 4) * 4096
                                         + n0 + bn8 * 8;
                r0 = *(const uint4*)(Bp);
                r1 = *(const uint4*)(Bp + 4096);
                r2 = *(const uint4*)(Bp + 8192);
                r3 = *(const uint4*)(Bp + 12288);
            }
        }
        __syncthreads();
        cur ^= 1;
    }

    // ---- epilogue; C/D: col=lane&31, row=(reg&3)+8*(reg>>2)+4*(lane>>5)
#pragma unroll
    for (int i = 0; i < 2; ++i)
#pragma unroll
        for (int j = 0; j < 4; ++j)
#pragma unroll
            for (int r = 0; r < 16; ++r) {
                int row = wm + 32 * i + (r & 3) + 8 * (r >> 2) + 4 * q;
                int col = n0 + wn + 32 * j + lm;
                int mg  = m0 + row;
                size_t ob = ((size_t)z * OC + mg) * 4096 + col;
                float v = acc[i][j][r] + bias[mA + row];
                if (EPI == 0) {
                    ((unsigned short*)outv)[ob] = f2bf(silu_f(v));
                } else if (EPI == 1) {
                    float g = bf2f(gate[((size_t)(b0 + z) * 1024 + mg) * 4096 + col]);
                    ((unsigned short*)outv)[ob] = f2bf(v * g);
                } else {
                    ((float*)outv)[ob] = silu_f(v);
                }
            }
}

// ---------------- fully-fused pool cascades (TMA x3 + RW x3).
// 512 threads/block, one plane/block; lane = column, each thread owns 8 rows
// in registers (v[8] only -- RW restart re-reads x_aux from global, which is
// L2/L3-hot). Horizontal taps via __shfl, vertical via two 16KB LDS transpose
// buffers. Small live state: no scratch spill (round-2 lesson: x0[16]+v[16]
// spilled -> 647MB HBM traffic). Arithmetic identical to passing versions.
__global__ __launch_bounds__(512, 4)
void pool_casc_both(const unsigned short* __restrict__ in,
                    unsigned short* __restrict__ t1, unsigned short* __restrict__ t2,
                    unsigned short* __restrict__ t3, unsigned short* __restrict__ r1,
                    unsigned short* __restrict__ r2, unsigned short* __restrict__ r3)
{
    __shared__ float ha[4096], hb[4096];
    const size_t base = (size_t)blockIdx.x * 4096;
    const int t    = threadIdx.x;
    const int lane = t & 63;       // column
    const int w    = t >> 6;       // wave id 0..7 -> rows w, w+8, ..., w+56

    const int il2 = (lane - 2) & 63, il1 = (lane - 1) & 63;
    const int ir1 = (lane + 1) & 63, ir2 = (lane + 2) & 63;
    const bool vl2 = lane >= 2, vl1 = lane >= 1;
    const bool vr1 = lane <= 62, vr2 = lane <= 61;

    float v[8];
#pragma unroll
    for (int k = 0; k < 8; ++k)
        v[k] = bf2f(in[base + (size_t)(w + 8 * k) * 64 + lane]);

    // ---- TMaxAvg cascade (3 stages)
#pragma unroll
    for (int s = 0; s < 3; ++s) {
        unsigned short* outp = (s == 0) ? t1 : (s == 1) ? t2 : t3;
        // horizontal: shuffles, write (max,sum) to ha/hb
#pragma unroll
        for (int k = 0; k < 8; ++k) {
            float c = v[k];
            float a2 = __shfl(c, il2, 64);
            float a1 = __shfl(c, il1, 64);
            float b1 = __shfl(c, ir1, 64);
            float b2 = __shfl(c, ir2, 64);
            float mx = -INFINITY, sm = 0.0f;
            mx = vl2 ? fmaxf(mx, a2) : mx;  sm = vl2 ? (sm + a2) : sm;
            mx = vl1 ? fmaxf(mx, a1) : mx;  sm = vl1 ? (sm + a1) : sm;
            mx = fmaxf(mx, c);              sm = sm + c;
            mx = vr1 ? fmaxf(mx, b1) : mx;  sm = vr1 ? (sm + b1) : sm;
            mx = vr2 ? fmaxf(mx, b2) : mx;  sm = vr2 ? (sm + b2) : sm;
            int r = w + 8 * k;
            ha[r * 64 + lane] = mx;
            hb[r * 64 + lane] = sm;
        }
        __syncthreads();
        // vertical: 5 taps from ha/hb (2 lanes/bank = free)
#pragma unroll
        for (int k = 0; k < 8; ++k) {
            int r = w + 8 * k;
            float mx = -INFINITY, sm = 0.0f;
#pragma unroll
            for (int dy = -2; dy <= 2; ++dy) {
                int rr = r + dy;
                if (0 <= rr && rr < 64) {
                    mx = fmaxf(mx, ha[rr * 64 + lane]);
                    sm += hb[rr * 64 + lane];
                }
            }
            float res = 0.9f * mx + 0.1f * (sm * (1.0f / 25.0f));
            v[k] = res;
            outp[base + (size_t)r * 64 + lane] = f2bf(res);
        }
        __syncthreads();
    }

    // ---- RW cascade (3 stages); restart from x_aux (L2/L3-hot re-read)
#pragma unroll
    for (int k = 0; k < 8; ++k)
        v[k] = bf2f(in[base + (size_t)(w + 8 * k) * 64 + lane]);
#pragma unroll
    for (int s = 0; s < 3; ++s) {
        unsigned short* outp = (s == 0) ? r1 : (s == 1) ? r2 : r3;
        // horizontal: e computed in-lane; shuffle both e and src
#pragma unroll
        for (int k = 0; k < 8; ++k) {
            float c = v[k];
            float e = expf(c);
            float ea2 = __shfl(e, il2, 64), ca2 = __shfl(c, il2, 64);
            float ea1 = __shfl(e, il1, 64), ca1 = __shfl(c, il1, 64);
            float eb1 = __shfl(e, ir1, 64), cb1 = __shfl(c, ir1, 64);
            float eb2 = __shfl(e, ir2, 64), cb2 = __shfl(c, ir2, 64);
            float se = 0.0f, sx = 0.0f;
            se = vl2 ? (se + ea2) : se;  sx = vl2 ? (sx + ea2 * ca2) : sx;
            se = vl1 ? (se + ea1) : se;  sx = vl1 ? (sx + ea1 * ca1) : sx;
            se = se + e;                 sx = sx + e * c;
            se = vr1 ? (se + eb1) : se;  sx = vr1 ? (sx + eb1 * cb1) : sx;
            se = vr2 ? (se + eb2) : se;  sx = vr2 ? (sx + eb2 * cb2) : sx;
            int r = w + 8 * k;
            ha[r * 64 + lane] = sx;
            hb[r * 64 + lane] = se;
        }
        __syncthreads();
        // vertical
#pragma unroll
        for (int k = 0; k < 8; ++k) {
            int r = w + 8 * k;
            float se = 0.0f, sx = 0.0f;
#pragma unroll
            for (int dy = -2; dy <= 2; ++dy) {
                int rr = r + dy;
                if (0 <= rr && rr < 64) {
                    sx += ha[rr * 64 + lane];
                    se += hb[rr * 64 + lane];
                }
            }
            float res = sx / (se + 1e-6f);
            v[k] = res;
            outp[base + (size_t)r * 64 + lane] = f2bf(res);
        }
        __syncthreads();
    }
}

// ---------------- fused LSKA depthwise chain for a batch-QUAD, bf16 io.
// Same structure as pool_casc_both: 512 threads, one channel-plane/block,
// lane = column, 8 rows/thread in registers. Horizontal convs (k=3, dil 1
// and dil 2) via __shfl +-1/+-2; vertical convs via 16KB LDS transpose
// buffers. fmaf order (center, left, right) identical to previous version.
__global__ __launch_bounds__(512, 4)
void lska_dw_quad(const unsigned short* __restrict__ Y2b, int b0,
                  const float* __restrict__ wh1, const float* __restrict__ bh1,
                  const float* __restrict__ wv1, const float* __restrict__ bv1,
                  const float* __restrict__ wh2, const float* __restrict__ bh2,
                  const float* __restrict__ wv2, const float* __restrict__ bv2,
                  unsigned short* __restrict__ outq)
{
    __shared__ float bufA[4096], bufB[4096];
    const int bi = blockIdx.x;
    const int zz = bi >> 10, c = bi & 1023;
    const unsigned short* src = Y2b + ((size_t)(b0 + zz) * 1024 + c) * 4096;
    unsigned short* dst = outq + (size_t)bi * 4096;
    const int t = threadIdx.x;
    const int lane = t & 63, w = t >> 6;

    const int il1 = (lane - 1) & 63, ir1 = (lane + 1) & 63;
    const int il2 = (lane - 2) & 63, ir2 = (lane + 2) & 63;
    const bool vl1 = lane >= 1, vr1 = lane <= 62;
    const bool vl2 = lane >= 2, vr2 = lane <= 61;

    const float h1w0 = wh1[c * 3], h1w1 = wh1[c * 3 + 1], h1w2 = wh1[c * 3 + 2], h1b = bh1[c];
    const float v1w0 = wv1[c * 3], v1w1 = wv1[c * 3 + 1], v1w2 = wv1[c * 3 + 2], v1b = bv1[c];
    const float h2w0 = wh2[c * 3], h2w1 = wh2[c * 3 + 1], h2w2 = wh2[c * 3 + 2], h2b = bh2[c];
    const float v2w0 = wv2[c * 3], v2w1 = wv2[c * 3 + 1], v2w2 = wv2[c * 3 + 2], v2b = bv2[c];

    float v[8];
#pragma unroll
    for (int k = 0; k < 8; ++k)
        v[k] = bf2f(src[(size_t)(w + 8 * k) * 64 + lane]);

    // H1 (dil 1): shuffles -> bufA
#pragma unroll
    for (int k = 0; k < 8; ++k) {
        float cv = v[k];
        float cl = __shfl(cv, il1, 64);
        float cr = __shfl(cv, ir1, 64);
        float a = fmaf(h1w1, cv, h1b);
        a = vl1 ? fmaf(h1w0, cl, a) : a;
        a = vr1 ? fmaf(h1w2, cr, a) : a;
        bufA[(w + 8 * k) * 64 + lane] = a;
    }
    __syncthreads();
    // V1 (dil 1): LDS taps -> reg
#pragma unroll
    for (int k = 0; k < 8; ++k) {
        int r = w + 8 * k;
        float a = fmaf(v1w1, bufA[r * 64 + lane], v1b);
        if (r >= 1)  a = fmaf(v1w0, bufA[(r - 1) * 64 + lane], a);
        if (r <= 62) a = fmaf(v1w2, bufA[(r + 1) * 64 + lane], a);
        v[k] = a;
    }
    // H2 (dil 2): shuffles -> bufB
#pragma unroll
    for (int k = 0; k < 8; ++k) {
        float cv = v[k];
        float cl = __shfl(cv, il2, 64);
        float cr = __shfl(cv, ir2, 64);
        float a = fmaf(h2w1, cv, h2b);
        a = vl2 ? fmaf(h2w0, cl, a) : a;
        a = vr2 ? fmaf(h2w2, cr, a) : a;
        bufB[(w + 8 * k) * 64 + lane] = a;
    }
    __syncthreads();
    // V2 (dil 2): LDS taps -> out
#pragma unroll
    for (int k = 0; k < 8; ++k) {
        int r = w + 8 * k;
        float a = fmaf(v2w1, bufB[r * 64 + lane], v2b);
        if (r >= 2)  a = fmaf(v2w0, bufB[(r - 2) * 64 + lane], a);
        if (r <= 61) a = fmaf(v2w2, bufB[(r + 2) * 64 + lane], a);
        dst[(size_t)r * 64 + lane] = f2bf(a);
    }
}

// ---------------- conversions
__global__ void f2bf_vec(const float* __restrict__ in, unsigned short* __restrict__ out)
{
    size_t i = ((size_t)blockIdx.x * 256 + threadIdx.x) * 8;
    float4 v0 = *(const float4*)(in + i);
    float4 v1 = *(const float4*)(in + i + 4);
    uint2 o0, o1;
    o0.x = (unsigned)f2bf(v0.x) | ((unsigned)f2bf(v0.y) << 16);
    o0.y = (unsigned)f2bf(v0.z) | ((unsigned)f2bf(v0.w) << 16);
    o1.x = (unsigned)f2bf(v1.x) | ((unsigned)f2bf(v1.y) << 16);
    o1.y = (unsigned)f2bf(v1.z) | ((unsigned)f2bf(v1.w) << 16);
    *(uint2*)(out + i) = o0;
    *(uint2*)(out + i + 4) = o1;
}

__global__ void wsplit(const float* __restrict__ w, unsigned short* __restrict__ wh,
                       unsigned short* __restrict__ wl)
{
    int i = blockIdx.x * 256 + threadIdx.x;
    float v = w[i];
    unsigned short h = f2bf(v);
    wh[i] = h;
    wl[i] = f2bf(v - bf2f(h));
}

extern "C" void kernel_launch(void* const* d_in, const int* in_sizes, int n_in,
                              void* d_out, int out_size, void* d_ws, size_t ws_size,
                              hipStream_t stream)
{
    const float* x       = (const float*)d_in[0];
    const float* w_sta   = (const float*)d_in[1];
    const float* b_sta   = (const float*)d_in[2];
    const float* w_cv1   = (const float*)d_in[3];
    const float* b_cv1   = (const float*)d_in[4];
    const float* w_cv2   = (const float*)d_in[5];
    const float* b_cv2   = (const float*)d_in[6];
    const float* w_cvend = (const float*)d_in[7];
    const float* b_cvend = (const float*)d_in[8];
    const float* w_dwh   = (const float*)d_in[9];
    const float* b_dwh   = (const float*)d_in[10];
    const float* w_dwv   = (const float*)d_in[11];
    const float* b_dwv   = (const float*)d_in[12];
    const float* w_ddwh  = (const float*)d_in[13];
    const float* b_ddwh  = (const float*)d_in[14];
    const float* w_ddwv  = (const float*)d_in[15];
    const float* b_ddwv  = (const float*)d_in[16];
    const float* w_c1    = (const float*)d_in[17];
    const float* b_c1    = (const float*)d_in[18];
    float* outf = (float*)d_out;
    unsigned short* Y2b = (unsigned short*)d_out;   // [8,1024,4096] bf16 = 67.1 MB

    // ws (bf16 element offsets), capacity 128 MiB = 67.1M shorts:
    //   phase 1-4: xaux, t1..t3, r1..r3 (7 x 8,388,608 shorts = 117.4 MB)
    //   WT weights hi/lo at +58,720,256 (5,505,024 shorts, ends 64.2M = 128.5 MB)
    // Overlays: xb (input bf16, 16.7M shorts) = t1..t2 (dead until pools run);
    //   phase-5: a4q = xaux+t1 (quad, 16.8M shorts),
    //            gq8 = t2..r2 (BOTH quads, 33.6M shorts, ends 50.3M < WT) --
    //            pools dead then; single cvend over all 8 batches.
    unsigned short* WS   = (unsigned short*)d_ws;
    unsigned short* xaux = WS;
    unsigned short* t1   = WS + 8388608;
    unsigned short* t2   = WS + 16777216;
    unsigned short* t3   = WS + 25165824;
    unsigned short* r1   = WS + 33554432;
    unsigned short* r2   = WS + 41943040;
    unsigned short* r3   = WS + 50331648;
    unsigned short* WT   = WS + 58720256;
    unsigned short* xb   = t1;
    unsigned short* a4q  = WS;
    unsigned short* gq8  = WS + 16777216;

    unsigned short* sta_h = WT,           * sta_l = WT + 131072;
    unsigned short* cv1_h = WT + 262144,  * cv1_l = WT + 786432;
    unsigned short* cv2_h = WT + 1310720, * cv2_l = WT + 1835008;
    unsigned short* c1_h  = WT + 2359296, * c1_l  = WT + 3407872;
    unsigned short* cve_h = WT + 4456448, * cve_l = WT + 4980736;

    dim3 blk(256);

    // 0) conversions
    f2bf_vec<<<8192, blk, 0, stream>>>(x, xb);
    wsplit<<<512,  blk, 0, stream>>>(w_sta,   sta_h, sta_l);
    wsplit<<<2048, blk, 0, stream>>>(w_cv1,   cv1_h, cv1_l);
    wsplit<<<2048, blk, 0, stream>>>(w_cv2,   cv2_h, cv2_l);
    wsplit<<<4096, blk, 0, stream>>>(w_c1,    c1_h,  c1_l);
    wsplit<<<2048, blk, 0, stream>>>(w_cvend, cve_h, cve_l);

    // 1) x_aux = SiLU(sta(x)) -> bf16 [8,256,4096]
    {
        BSlots s; s.p[0] = xb; s.p[1] = xb + 1048576; s.p[2] = xb; s.p[3] = xb;
        gemm_mfma<0><<<dim3(16, 2, 8), blk, 0, stream>>>(
            sta_h, sta_l, nullptr, nullptr, 512, s, s, 2097152L,
            b_sta, nullptr, xaux, 256, nullptr, 0, 512);
    }

    // 2+3) fused pool cascades: TMA -> t1,t2,t3 and RW -> r1,r2,r3
    //      (t1 overwrites xb, which is dead after the sta GEMM)
    pool_casc_both<<<2048, dim3(512), 0, stream>>>(xaux, t1, t2, t3, r1, r2, r3);

    // 4) merged cv1+cv2 -> Y2b channels [0,512)=cv1, [512,1024)=cv2
    {
        BSlots s1; s1.p[0] = xaux; s1.p[1] = t1; s1.p[2] = t2; s1.p[3] = t3;
        BSlots s2; s2.p[0] = xaux; s2.p[1] = r1; s2.p[2] = r2; s2.p[3] = r3;
        gemm_mfma<0><<<dim3(16, 8, 8), blk, 0, stream>>>(
            cv1_h, cv1_l, cv2_h, cv2_l, 1024, s1, s2, 1048576L,
            b_cv1, b_cv2, Y2b, 1024, nullptr, 0, 1024);
    }

    // 5) per quad: dw chain -> a4q ; gated c1 -> gq8[qd]
    for (int qd = 0; qd < 2; ++qd) {
        const int b0 = 4 * qd;
        lska_dw_quad<<<4096, dim3(512), 0, stream>>>(Y2b, b0,
                                               w_dwh, b_dwh, w_dwv, b_dwv,
                                               w_ddwh, b_ddwh, w_ddwv, b_ddwv, a4q);
        {
            BSlots s; s.p[0] = a4q; s.p[1] = a4q + 1048576;
            s.p[2] = a4q + 2097152; s.p[3] = a4q + 3145728;
            gemm_mfma<1><<<dim3(16, 8, 4), blk, 0, stream>>>(
                c1_h, c1_l, nullptr, nullptr, 1024, s, s, 4194304L,
                b_c1, nullptr, gq8 + (size_t)qd * 16777216, 1024, Y2b, b0, 1024);
        }
    }
    // 6) single cvend over all 8 batches (Y2b dead now) -> d_out f32
    {
        BSlots s; s.p[0] = gq8; s.p[1] = gq8 + 1048576;
        s.p[2] = gq8 + 2097152; s.p[3] = gq8 + 3145728;
        gemm_mfma<2><<<dim3(16, 4, 8), blk, 0, stream>>>(
            cve_h, cve_l, nullptr, nullptr, 1024, s, s, 4194304L,
            b_cvend, nullptr, outf, 512, nullptr, 0, 1024);
    }
}

// Round 8
// 738.186 us; speedup vs baseline: 1.0992x; 1.0992x over previous
//
#include <hip/hip_runtime.h>
#include <math.h>

typedef __attribute__((ext_vector_type(8))) short short8;
typedef __attribute__((ext_vector_type(16))) float floatx16;

__device__ __forceinline__ float silu_f(float v) { return v / (1.0f + expf(-v)); }
__device__ __forceinline__ float bf2f(unsigned short u) {
    unsigned int x = ((unsigned int)u) << 16;
    return __uint_as_float(x);
}
__device__ __forceinline__ unsigned short f2bf(float f) {
    unsigned int u = __float_as_uint(f);
    u += 0x7FFFu + ((u >> 16) & 1u);
    return (unsigned short)(u >> 16);
}

struct BSlots { const unsigned short* p[4]; };

// ---------------- bf16 MFMA GEMM (1x1 conv), software-prefetched:
// out[(z*OC+m)*4096+n] = EPI( sum_k (Ah+Al)[m][k] * B[k][n] + bias[m] )
// ROUND-4 PROVEN STRUCTURE (177us, MfmaUtil 34.8%): 128x256 tile, 256 thr,
// 2 barriers/K-step, prefetch issued AFTER barrier 2 (overlaps compute).
// Rounds 5-7 falsified: 256^2 tile (neutral), single-barrier dbuf (regressed).
// Dual-branch: if Ahp2 != null and m0>=512, use (Ahp2,Alp2,bias2,bs2) with
// branch-local row mA = m0-512 (merged cv1/cv2 dispatch).
// EPI: 0 = SiLU -> bf16; 1 = gate-mult by Y2b -> bf16; 2 = SiLU -> f32
#define APITCH 36   // bf16 elems per A LDS row (32 data + 4 pad)
#define BPITCH 18   // dwords per B LDS row (16 data + 2 pad), k-pairs per dword

template <int EPI>
__global__ __launch_bounds__(256, 2)
void gemm_mfma(const unsigned short* __restrict__ Ahp,
               const unsigned short* __restrict__ Alp,
               const unsigned short* __restrict__ Ahp2,
               const unsigned short* __restrict__ Alp2, int ldK,
               BSlots bs, BSlots bs2, long bstride,
               const float* __restrict__ bias, const float* __restrict__ bias2,
               void* __restrict__ outv, int OC,
               const unsigned short* __restrict__ gate, int b0, int K)
{
    __shared__ __align__(16) unsigned short As[2][128 * APITCH];
    __shared__ __align__(16) unsigned int   Bsm[256 * BPITCH];

    const int t  = threadIdx.x;
    const int z  = blockIdx.z;
    const int m0 = blockIdx.y * 128;
    const int n0 = blockIdx.x * 256;

    int mA = m0;
    if (Ahp2 != nullptr && m0 >= 512) {
        Ahp = Ahp2; Alp = Alp2; bias = bias2; bs = bs2; mA = m0 - 512;
    }

    // staging ids
    const int am = t >> 1, ahf = t & 1;          // A: row, k-half (16 elems)
    const int bkg = t & 7, bn8 = t >> 3;         // B: k-group (4 rows), n-octet

    // compute ids
    const int w = t >> 6, lane = t & 63;
    const int wm = (w & 1) * 64, wn = (w >> 1) * 128;
    const int lm = lane & 31, q = lane >> 5;

    floatx16 acc[2][4];
#pragma unroll
    for (int i = 0; i < 2; ++i)
#pragma unroll
        for (int j = 0; j < 4; ++j)
#pragma unroll
            for (int r = 0; r < 16; ++r) acc[i][j][r] = 0.0f;

    const unsigned short* Aph = Ahp + (size_t)(mA + am) * ldK + ahf * 16;
    const unsigned short* Apl = Alp + (size_t)(mA + am) * ldK + ahf * 16;

    uint4 ah0, ah1, al0, al1, r0, r1, r2, r3;
    // ---- prefetch tile 0
    {
        ah0 = *(const uint4*)(Aph);
        ah1 = *(const uint4*)(Aph + 8);
        al0 = *(const uint4*)(Apl);
        al1 = *(const uint4*)(Apl + 8);
        const unsigned short* Bp = bs.p[0] + (size_t)z * bstride
                                 + (size_t)(bkg * 4) * 4096 + n0 + bn8 * 8;
        r0 = *(const uint4*)(Bp);
        r1 = *(const uint4*)(Bp + 4096);
        r2 = *(const uint4*)(Bp + 8192);
        r3 = *(const uint4*)(Bp + 12288);
    }

    for (int k0 = 0; k0 < K; k0 += 32) {
        __syncthreads();   // previous iteration's frag reads done

        // ---- stage A tile: [m][k] bf16, pitch 36 (conflict-minimal)
        {
            unsigned short* Ad0 = &As[0][am * APITCH + ahf * 16];
            unsigned short* Ad1 = &As[1][am * APITCH + ahf * 16];
            ((uint2*)Ad0)[0] = *((const uint2*)&ah0);
            ((uint2*)Ad0)[1] = *((const uint2*)&ah0 + 1);
            ((uint2*)Ad0)[2] = *((const uint2*)&ah1);
            ((uint2*)Ad0)[3] = *((const uint2*)&ah1 + 1);
            ((uint2*)Ad1)[0] = *((const uint2*)&al0);
            ((uint2*)Ad1)[1] = *((const uint2*)&al0 + 1);
            ((uint2*)Ad1)[2] = *((const uint2*)&al1);
            ((uint2*)Ad1)[3] = *((const uint2*)&al1 + 1);
        }
        // ---- stage B tile: transposed [n][k-pair dwords], pitch 18 dwords.
        // store banks: 16*(bn8&1) + 18*i + 2*bkg -> 16 bank-pairs x 4 lanes = min
        {
            const unsigned int* d0 = (const unsigned int*)&r0;
            const unsigned int* d1 = (const unsigned int*)&r1;
            const unsigned int* d2 = (const unsigned int*)&r2;
            const unsigned int* d3 = (const unsigned int*)&r3;
#pragma unroll
            for (int i = 0; i < 8; ++i) {
                unsigned int sel = (i & 1) ? 0x07060302u : 0x05040100u;
                uint2 pv;
                pv.x = __builtin_amdgcn_perm(d1[i >> 1], d0[i >> 1], sel);
                pv.y = __builtin_amdgcn_perm(d3[i >> 1], d2[i >> 1], sel);
                *(uint2*)&Bsm[(bn8 * 8 + i) * BPITCH + bkg * 2] = pv;
            }
        }
        __syncthreads();

        // ---- issue prefetch for next tile (covered by compute below)
        const int k1 = k0 + 32;
        if (k1 < K) {
            ah0 = *(const uint4*)(Aph + k1);
            ah1 = *(const uint4*)(Aph + k1 + 8);
            al0 = *(const uint4*)(Apl + k1);
            al1 = *(const uint4*)(Apl + k1 + 8);
            const unsigned short* Bp = bs.p[k1 >> 8] + (size_t)z * bstride
                                     + (size_t)((k1 & 255) + bkg * 4) * 4096
                                     + n0 + bn8 * 8;
            r0 = *(const uint4*)(Bp);
            r1 = *(const uint4*)(Bp + 4096);
            r2 = *(const uint4*)(Bp + 8192);
            r3 = *(const uint4*)(Bp + 12288);
        }

        // ---- compute: 2 k-steps x (2 m-tiles x 4 n-tiles) x (hi+lo)
#pragma unroll
        for (int s = 0; s < 2; ++s) {
            union { short8 v; uint2 u[2]; } afh[2], afl[2], bfr[4];
#pragma unroll
            for (int i = 0; i < 2; ++i) {
                int rb = (wm + 32 * i + lm) * APITCH + s * 16 + q * 8;
                afh[i].u[0] = *(const uint2*)&As[0][rb];
                afh[i].u[1] = *(const uint2*)&As[0][rb + 4];
                afl[i].u[0] = *(const uint2*)&As[1][rb];
                afl[i].u[1] = *(const uint2*)&As[1][rb + 4];
            }
#pragma unroll
            for (int j = 0; j < 4; ++j) {
                int nb = (wn + 32 * j + lm) * BPITCH + s * 8 + q * 4;
                bfr[j].u[0] = *(const uint2*)&Bsm[nb];
                bfr[j].u[1] = *(const uint2*)&Bsm[nb + 2];
            }
#pragma unroll
            for (int i = 0; i < 2; ++i)
#pragma unroll
                for (int j = 0; j < 4; ++j) {
                    acc[i][j] = __builtin_amdgcn_mfma_f32_32x32x16_bf16(
                        afh[i].v, bfr[j].v, acc[i][j], 0, 0, 0);
                    acc[i][j] = __builtin_amdgcn_mfma_f32_32x32x16_bf16(
                        afl[i].v, bfr[j].v, acc[i][j], 0, 0, 0);
                }
        }
    }

    // ---- epilogue; C/D: col=lane&31, row=(reg&3)+8*(reg>>2)+4*(lane>>5)
#pragma unroll
    for (int i = 0; i < 2; ++i)
#pragma unroll
        for (int j = 0; j < 4; ++j)
#pragma unroll
            for (int r = 0; r < 16; ++r) {
                int row = wm + 32 * i + (r & 3) + 8 * (r >> 2) + 4 * q;
                int col = n0 + wn + 32 * j + lm;
                int mg  = m0 + row;
                size_t ob = ((size_t)z * OC + mg) * 4096 + col;
                float v = acc[i][j][r] + bias[mA + row];
                if (EPI == 0) {
                    ((unsigned short*)outv)[ob] = f2bf(silu_f(v));
                } else if (EPI == 1) {
                    float g = bf2f(gate[((size_t)(b0 + z) * 1024 + mg) * 4096 + col]);
                    ((unsigned short*)outv)[ob] = f2bf(v * g);
                } else {
                    ((float*)outv)[ob] = silu_f(v);
                }
            }
}

// ---------------- fully-fused pool cascades (TMA x3 + RW x3).
// 512 threads/block, one plane/block; lane = column, each thread owns 8 rows
// in registers (v[8] only -- RW restart re-reads x_aux from global, which is
// L2/L3-hot). Horizontal taps via __shfl, vertical via two 16KB LDS transpose
// buffers. Small live state: no scratch spill (round-2 lesson: x0[16]+v[16]
// spilled -> 647MB HBM traffic). Arithmetic identical to passing versions.
__global__ __launch_bounds__(512, 4)
void pool_casc_both(const unsigned short* __restrict__ in,
                    unsigned short* __restrict__ t1, unsigned short* __restrict__ t2,
                    unsigned short* __restrict__ t3, unsigned short* __restrict__ r1,
                    unsigned short* __restrict__ r2, unsigned short* __restrict__ r3)
{
    __shared__ float ha[4096], hb[4096];
    const size_t base = (size_t)blockIdx.x * 4096;
    const int t    = threadIdx.x;
    const int lane = t & 63;       // column
    const int w    = t >> 6;       // wave id 0..7 -> rows w, w+8, ..., w+56

    const int il2 = (lane - 2) & 63, il1 = (lane - 1) & 63;
    const int ir1 = (lane + 1) & 63, ir2 = (lane + 2) & 63;
    const bool vl2 = lane >= 2, vl1 = lane >= 1;
    const bool vr1 = lane <= 62, vr2 = lane <= 61;

    float v[8];
#pragma unroll
    for (int k = 0; k < 8; ++k)
        v[k] = bf2f(in[base + (size_t)(w + 8 * k) * 64 + lane]);

    // ---- TMaxAvg cascade (3 stages)
#pragma unroll
    for (int s = 0; s < 3; ++s) {
        unsigned short* outp = (s == 0) ? t1 : (s == 1) ? t2 : t3;
        // horizontal: shuffles, write (max,sum) to ha/hb
#pragma unroll
        for (int k = 0; k < 8; ++k) {
            float c = v[k];
            float a2 = __shfl(c, il2, 64);
            float a1 = __shfl(c, il1, 64);
            float b1 = __shfl(c, ir1, 64);
            float b2 = __shfl(c, ir2, 64);
            float mx = -INFINITY, sm = 0.0f;
            mx = vl2 ? fmaxf(mx, a2) : mx;  sm = vl2 ? (sm + a2) : sm;
            mx = vl1 ? fmaxf(mx, a1) : mx;  sm = vl1 ? (sm + a1) : sm;
            mx = fmaxf(mx, c);              sm = sm + c;
            mx = vr1 ? fmaxf(mx, b1) : mx;  sm = vr1 ? (sm + b1) : sm;
            mx = vr2 ? fmaxf(mx, b2) : mx;  sm = vr2 ? (sm + b2) : sm;
            int r = w + 8 * k;
            ha[r * 64 + lane] = mx;
            hb[r * 64 + lane] = sm;
        }
        __syncthreads();
        // vertical: 5 taps from ha/hb (2 lanes/bank = free)
#pragma unroll
        for (int k = 0; k < 8; ++k) {
            int r = w + 8 * k;
            float mx = -INFINITY, sm = 0.0f;
#pragma unroll
            for (int dy = -2; dy <= 2; ++dy) {
                int rr = r + dy;
                if (0 <= rr && rr < 64) {
                    mx = fmaxf(mx, ha[rr * 64 + lane]);
                    sm += hb[rr * 64 + lane];
                }
            }
            float res = 0.9f * mx + 0.1f * (sm * (1.0f / 25.0f));
            v[k] = res;
            outp[base + (size_t)r * 64 + lane] = f2bf(res);
        }
        __syncthreads();
    }

    // ---- RW cascade (3 stages); restart from x_aux (L2/L3-hot re-read)
#pragma unroll
    for (int k = 0; k < 8; ++k)
        v[k] = bf2f(in[base + (size_t)(w + 8 * k) * 64 + lane]);
#pragma unroll
    for (int s = 0; s < 3; ++s) {
        unsigned short* outp = (s == 0) ? r1 : (s == 1) ? r2 : r3;
        // horizontal: e computed in-lane; shuffle both e and src
#pragma unroll
        for (int k = 0; k < 8; ++k) {
            float c = v[k];
            float e = expf(c);
            float ea2 = __shfl(e, il2, 64), ca2 = __shfl(c, il2, 64);
            float ea1 = __shfl(e, il1, 64), ca1 = __shfl(c, il1, 64);
            float eb1 = __shfl(e, ir1, 64), cb1 = __shfl(c, ir1, 64);
            float eb2 = __shfl(e, ir2, 64), cb2 = __shfl(c, ir2, 64);
            float se = 0.0f, sx = 0.0f;
            se = vl2 ? (se + ea2) : se;  sx = vl2 ? (sx + ea2 * ca2) : sx;
            se = vl1 ? (se + ea1) : se;  sx = vl1 ? (sx + ea1 * ca1) : sx;
            se = se + e;                 sx = sx + e * c;
            se = vr1 ? (se + eb1) : se;  sx = vr1 ? (sx + eb1 * cb1) : sx;
            se = vr2 ? (se + eb2) : se;  sx = vr2 ? (sx + eb2 * cb2) : sx;
            int r = w + 8 * k;
            ha[r * 64 + lane] = sx;
            hb[r * 64 + lane] = se;
        }
        __syncthreads();
        // vertical
#pragma unroll
        for (int k = 0; k < 8; ++k) {
            int r = w + 8 * k;
            float se = 0.0f, sx = 0.0f;
#pragma unroll
            for (int dy = -2; dy <= 2; ++dy) {
                int rr = r + dy;
                if (0 <= rr && rr < 64) {
                    sx += ha[rr * 64 + lane];
                    se += hb[rr * 64 + lane];
                }
            }
            float res = sx / (se + 1e-6f);
            v[k] = res;
            outp[base + (size_t)r * 64 + lane] = f2bf(res);
        }
        __syncthreads();
    }
}

// ---------------- fused LSKA depthwise chain for a batch-QUAD, bf16 io.
// Same structure as pool_casc_both: 512 threads, one channel-plane/block,
// lane = column, 8 rows/thread in registers. Horizontal convs (k=3, dil 1
// and dil 2) via __shfl +-1/+-2; vertical convs via 16KB LDS transpose
// buffers. fmaf order (center, left, right) identical to previous version.
__global__ __launch_bounds__(512, 4)
void lska_dw_quad(const unsigned short* __restrict__ Y2b, int b0,
                  const float* __restrict__ wh1, const float* __restrict__ bh1,
                  const float* __restrict__ wv1, const float* __restrict__ bv1,
                  const float* __restrict__ wh2, const float* __restrict__ bh2,
                  const float* __restrict__ wv2, const float* __restrict__ bv2,
                  unsigned short* __restrict__ outq)
{
    __shared__ float bufA[4096], bufB[4096];
    const int bi = blockIdx.x;
    const int zz = bi >> 10, c = bi & 1023;
    const unsigned short* src = Y2b + ((size_t)(b0 + zz) * 1024 + c) * 4096;
    unsigned short* dst = outq + (size_t)bi * 4096;
    const int t = threadIdx.x;
    const int lane = t & 63, w = t >> 6;

    const int il1 = (lane - 1) & 63, ir1 = (lane + 1) & 63;
    const int il2 = (lane - 2) & 63, ir2 = (lane + 2) & 63;
    const bool vl1 = lane >= 1, vr1 = lane <= 62;
    const bool vl2 = lane >= 2, vr2 = lane <= 61;

    const float h1w0 = wh1[c * 3], h1w1 = wh1[c * 3 + 1], h1w2 = wh1[c * 3 + 2], h1b = bh1[c];
    const float v1w0 = wv1[c * 3], v1w1 = wv1[c * 3 + 1], v1w2 = wv1[c * 3 + 2], v1b = bv1[c];
    const float h2w0 = wh2[c * 3], h2w1 = wh2[c * 3 + 1], h2w2 = wh2[c * 3 + 2], h2b = bh2[c];
    const float v2w0 = wv2[c * 3], v2w1 = wv2[c * 3 + 1], v2w2 = wv2[c * 3 + 2], v2b = bv2[c];

    float v[8];
#pragma unroll
    for (int k = 0; k < 8; ++k)
        v[k] = bf2f(src[(size_t)(w + 8 * k) * 64 + lane]);

    // H1 (dil 1): shuffles -> bufA
#pragma unroll
    for (int k = 0; k < 8; ++k) {
        float cv = v[k];
        float cl = __shfl(cv, il1, 64);
        float cr = __shfl(cv, ir1, 64);
        float a = fmaf(h1w1, cv, h1b);
        a = vl1 ? fmaf(h1w0, cl, a) : a;
        a = vr1 ? fmaf(h1w2, cr, a) : a;
        bufA[(w + 8 * k) * 64 + lane] = a;
    }
    __syncthreads();
    // V1 (dil 1): LDS taps -> reg
#pragma unroll
    for (int k = 0; k < 8; ++k) {
        int r = w + 8 * k;
        float a = fmaf(v1w1, bufA[r * 64 + lane], v1b);
        if (r >= 1)  a = fmaf(v1w0, bufA[(r - 1) * 64 + lane], a);
        if (r <= 62) a = fmaf(v1w2, bufA[(r + 1) * 64 + lane], a);
        v[k] = a;
    }
    // H2 (dil 2): shuffles -> bufB
#pragma unroll
    for (int k = 0; k < 8; ++k) {
        float cv = v[k];
        float cl = __shfl(cv, il2, 64);
        float cr = __shfl(cv, ir2, 64);
        float a = fmaf(h2w1, cv, h2b);
        a = vl2 ? fmaf(h2w0, cl, a) : a;
        a = vr2 ? fmaf(h2w2, cr, a) : a;
        bufB[(w + 8 * k) * 64 + lane] = a;
    }
    __syncthreads();
    // V2 (dil 2): LDS taps -> out
#pragma unroll
    for (int k = 0; k < 8; ++k) {
        int r = w + 8 * k;
        float a = fmaf(v2w1, bufB[r * 64 + lane], v2b);
        if (r >= 2)  a = fmaf(v2w0, bufB[(r - 2) * 64 + lane], a);
        if (r <= 61) a = fmaf(v2w2, bufB[(r + 2) * 64 + lane], a);
        dst[(size_t)r * 64 + lane] = f2bf(a);
    }
}

// ---------------- conversions
__global__ void f2bf_vec(const float* __restrict__ in, unsigned short* __restrict__ out)
{
    size_t i = ((size_t)blockIdx.x * 256 + threadIdx.x) * 8;
    float4 v0 = *(const float4*)(in + i);
    float4 v1 = *(const float4*)(in + i + 4);
    uint2 o0, o1;
    o0.x = (unsigned)f2bf(v0.x) | ((unsigned)f2bf(v0.y) << 16);
    o0.y = (unsigned)f2bf(v0.z) | ((unsigned)f2bf(v0.w) << 16);
    o1.x = (unsigned)f2bf(v1.x) | ((unsigned)f2bf(v1.y) << 16);
    o1.y = (unsigned)f2bf(v1.z) | ((unsigned)f2bf(v1.w) << 16);
    *(uint2*)(out + i) = o0;
    *(uint2*)(out + i + 4) = o1;
}

// all 5 weight hi/lo splits in one dispatch; blockIdx.y = segment,
// oversized segments exit early (grid.x sized for the largest).
struct WSeg { const float* src; unsigned short* dh; unsigned short* dl; int n; };
struct WTab { WSeg s[5]; };

__global__ void wsplit_all(WTab tab)
{
    const WSeg w = tab.s[blockIdx.y];
    const int i = blockIdx.x * 256 + threadIdx.x;
    if (i >= w.n) return;
    float v = w.src[i];
    unsigned short h = f2bf(v);
    w.dh[i] = h;
    w.dl[i] = f2bf(v - bf2f(h));
}

extern "C" void kernel_launch(void* const* d_in, const int* in_sizes, int n_in,
                              void* d_out, int out_size, void* d_ws, size_t ws_size,
                              hipStream_t stream)
{
    const float* x       = (const float*)d_in[0];
    const float* w_sta   = (const float*)d_in[1];
    const float* b_sta   = (const float*)d_in[2];
    const float* w_cv1   = (const float*)d_in[3];
    const float* b_cv1   = (const float*)d_in[4];
    const float* w_cv2   = (const float*)d_in[5];
    const float* b_cv2   = (const float*)d_in[6];
    const float* w_cvend = (const float*)d_in[7];
    const float* b_cvend = (const float*)d_in[8];
    const float* w_dwh   = (const float*)d_in[9];
    const float* b_dwh   = (const float*)d_in[10];
    const float* w_dwv   = (const float*)d_in[11];
    const float* b_dwv   = (const float*)d_in[12];
    const float* w_ddwh  = (const float*)d_in[13];
    const float* b_ddwh  = (const float*)d_in[14];
    const float* w_ddwv  = (const float*)d_in[15];
    const float* b_ddwv  = (const float*)d_in[16];
    const float* w_c1    = (const float*)d_in[17];
    const float* b_c1    = (const float*)d_in[18];
    float* outf = (float*)d_out;
    unsigned short* Y2b = (unsigned short*)d_out;   // [8,1024,4096] bf16 = 67.1 MB

    // ws (bf16 element offsets), capacity 128 MiB = 67.1M shorts:
    //   phase 1-4: xaux, t1..t3, r1..r3 (7 x 8,388,608 shorts = 117.4 MB)
    //   WT weights hi/lo at +58,720,256 (5,505,024 shorts, ends 64.2M = 128.5 MB)
    // Overlays: xb (input bf16, 16.7M shorts) = t1..t2 (dead until pools run);
    //   phase-5: a4q = xaux+t1 (quad, 16.8M shorts),
    //            gq8 = t2..r2 (BOTH quads, 33.6M shorts, ends 50.3M < WT) --
    //            pools dead then; single cvend over all 8 batches.
    unsigned short* WS   = (unsigned short*)d_ws;
    unsigned short* xaux = WS;
    unsigned short* t1   = WS + 8388608;
    unsigned short* t2   = WS + 16777216;
    unsigned short* t3   = WS + 25165824;
    unsigned short* r1   = WS + 33554432;
    unsigned short* r2   = WS + 41943040;
    unsigned short* r3   = WS + 50331648;
    unsigned short* WT   = WS + 58720256;
    unsigned short* xb   = t1;
    unsigned short* a4q  = WS;
    unsigned short* gq8  = WS + 16777216;

    unsigned short* sta_h = WT,           * sta_l = WT + 131072;
    unsigned short* cv1_h = WT + 262144,  * cv1_l = WT + 786432;
    unsigned short* cv2_h = WT + 1310720, * cv2_l = WT + 1835008;
    unsigned short* c1_h  = WT + 2359296, * c1_l  = WT + 3407872;
    unsigned short* cve_h = WT + 4456448, * cve_l = WT + 4980736;

    dim3 blk(256);

    // 0) conversions (input cast + all weight splits in one dispatch)
    f2bf_vec<<<8192, blk, 0, stream>>>(x, xb);
    {
        WTab tab;
        tab.s[0] = { w_sta,   sta_h, sta_l, 131072  };
        tab.s[1] = { w_cv1,   cv1_h, cv1_l, 524288  };
        tab.s[2] = { w_cv2,   cv2_h, cv2_l, 524288  };
        tab.s[3] = { w_c1,    c1_h,  c1_l,  1048576 };
        tab.s[4] = { w_cvend, cve_h, cve_l, 524288  };
        wsplit_all<<<dim3(4096, 5), blk, 0, stream>>>(tab);
    }

    // 1) x_aux = SiLU(sta(x)) -> bf16 [8,256,4096]
    {
        BSlots s; s.p[0] = xb; s.p[1] = xb + 1048576; s.p[2] = xb; s.p[3] = xb;
        gemm_mfma<0><<<dim3(16, 2, 8), blk, 0, stream>>>(
            sta_h, sta_l, nullptr, nullptr, 512, s, s, 2097152L,
            b_sta, nullptr, xaux, 256, nullptr, 0, 512);
    }

    // 2+3) fused pool cascades: TMA -> t1,t2,t3 and RW -> r1,r2,r3
    //      (t1 overwrites xb, which is dead after the sta GEMM)
    pool_casc_both<<<2048, dim3(512), 0, stream>>>(xaux, t1, t2, t3, r1, r2, r3);

    // 4) merged cv1+cv2 -> Y2b channels [0,512)=cv1, [512,1024)=cv2
    {
        BSlots s1; s1.p[0] = xaux; s1.p[1] = t1; s1.p[2] = t2; s1.p[3] = t3;
        BSlots s2; s2.p[0] = xaux; s2.p[1] = r1; s2.p[2] = r2; s2.p[3] = r3;
        gemm_mfma<0><<<dim3(16, 8, 8), blk, 0, stream>>>(
            cv1_h, cv1_l, cv2_h, cv2_l, 1024, s1, s2, 1048576L,
            b_cv1, b_cv2, Y2b, 1024, nullptr, 0, 1024);
    }

    // 5) per quad: dw chain -> a4q ; gated c1 -> gq8[qd]
    for (int qd = 0; qd < 2; ++qd) {
        const int b0 = 4 * qd;
        lska_dw_quad<<<4096, dim3(512), 0, stream>>>(Y2b, b0,
                                               w_dwh, b_dwh, w_dwv, b_dwv,
                                               w_ddwh, b_ddwh, w_ddwv, b_ddwv, a4q);
        {
            BSlots s; s.p[0] = a4q; s.p[1] = a4q + 1048576;
            s.p[2] = a4q + 2097152; s.p[3] = a4q + 3145728;
            gemm_mfma<1><<<dim3(16, 8, 4), blk, 0, stream>>>(
                c1_h, c1_l, nullptr, nullptr, 1024, s, s, 4194304L,
                b_c1, nullptr, gq8 + (size_t)qd * 16777216, 1024, Y2b, b0, 1024);
        }
    }
    // 6) single cvend over all 8 batches (Y2b dead now) -> d_out f32
    {
        BSlots s; s.p[0] = gq8; s.p[1] = gq8 + 1048576;
        s.p[2] = gq8 + 2097152; s.p[3] = gq8 + 3145728;
        gemm_mfma<2><<<dim3(16, 4, 8), blk, 0, stream>>>(
            cve_h, cve_l, nullptr, nullptr, 1024, s, s, 4194304L,
            b_cvend, nullptr, outf, 512, nullptr, 0, 1024);
    }
}

// Round 11
// 730.106 us; speedup vs baseline: 1.1114x; 1.0111x over previous
//
#include <hip/hip_runtime.h>
#include <math.h>

typedef __attribute__((ext_vector_type(8))) short short8;
typedef __attribute__((ext_vector_type(16))) float floatx16;

__device__ __forceinline__ float silu_f(float v) { return v / (1.0f + expf(-v)); }
__device__ __forceinline__ float bf2f(unsigned short u) {
    unsigned int x = ((unsigned int)u) << 16;
    return __uint_as_float(x);
}
__device__ __forceinline__ unsigned short f2bf(float f) {
    unsigned int u = __float_as_uint(f);
    u += 0x7FFFu + ((u >> 16) & 1u);
    return (unsigned short)(u >> 16);
}

struct BSlots { const unsigned short* p[4]; };

// ---------------- bf16 MFMA GEMM (1x1 conv), software-prefetched:
// out[(z*OC+m)*4096+n] = EPI( sum_k (Ah+Al)[m][k] * B[k][n] + bias[m] )
// Round-4 proven 2-barrier loop (177us/34.8%), now with DEPTH-2 register
// prefetch for B: two B reg sets (even/odd K-tiles), each issued 2 iters
// ahead -> ~2 compute phases (>1100cy) to cover HBM latency (~900cy).
// A (L2-hot weights) stays depth-1. K-loop unrolled x2 with static reg
// names (no runtime-indexed reg arrays -> no scratch).
// Dual-branch: if Ahp2 != null and m0>=512, use (Ahp2,Alp2,bias2,bs2) with
// branch-local row mA = m0-512 (merged cv1/cv2 dispatch).
// EPI: 0 = SiLU -> bf16; 1 = gate-mult by Y2b -> bf16; 2 = SiLU -> f32
#define APITCH 36   // bf16 elems per A LDS row (32 data + 4 pad)
#define BPITCH 18   // dwords per B LDS row (16 data + 2 pad), k-pairs per dword

template <int EPI>
__global__ __launch_bounds__(256, 2)
void gemm_mfma(const unsigned short* __restrict__ Ahp,
               const unsigned short* __restrict__ Alp,
               const unsigned short* __restrict__ Ahp2,
               const unsigned short* __restrict__ Alp2, int ldK,
               BSlots bs, BSlots bs2, long bstride,
               const float* __restrict__ bias, const float* __restrict__ bias2,
               void* __restrict__ outv, int OC,
               const unsigned short* __restrict__ gate, int b0, int K)
{
    __shared__ __align__(16) unsigned short As[2][128 * APITCH];
    __shared__ __align__(16) unsigned int   Bsm[256 * BPITCH];

    const int t  = threadIdx.x;
    const int z  = blockIdx.z;
    const int m0 = blockIdx.y * 128;
    const int n0 = blockIdx.x * 256;

    int mA = m0;
    if (Ahp2 != nullptr && m0 >= 512) {
        Ahp = Ahp2; Alp = Alp2; bias = bias2; bs = bs2; mA = m0 - 512;
    }

    // staging ids
    const int am = t >> 1, ahf = t & 1;          // A: row, k-half (16 elems)
    const int bkg = t & 7, bn8 = t >> 3;         // B: k-group (4 rows), n-octet

    // compute ids
    const int w = t >> 6, lane = t & 63;
    const int wm = (w & 1) * 64, wn = (w >> 1) * 128;
    const int lm = lane & 31, q = lane >> 5;

    floatx16 acc[2][4];
#pragma unroll
    for (int i = 0; i < 2; ++i)
#pragma unroll
        for (int j = 0; j < 4; ++j)
#pragma unroll
            for (int r = 0; r < 16; ++r) acc[i][j][r] = 0.0f;

    const unsigned short* Aph = Ahp + (size_t)(mA + am) * ldK + ahf * 16;
    const unsigned short* Apl = Alp + (size_t)(mA + am) * ldK + ahf * 16;

    uint4 ah0, ah1, al0, al1;
    uint4 pB0, pB1, pB2, pB3;                       // B even tiles (k0%64==0)
    uint4 qB0 = {0,0,0,0}, qB1 = {0,0,0,0};         // B odd tiles
    uint4 qB2 = {0,0,0,0}, qB3 = {0,0,0,0};

    // ---- prologue: A tile 0; B tiles 0 and 1
    {
        ah0 = *(const uint4*)(Aph);
        ah1 = *(const uint4*)(Aph + 8);
        al0 = *(const uint4*)(Apl);
        al1 = *(const uint4*)(Apl + 8);
        const unsigned short* Bp = bs.p[0] + (size_t)z * bstride
                                 + (size_t)(bkg * 4) * 4096 + n0 + bn8 * 8;
        pB0 = *(const uint4*)(Bp);
        pB1 = *(const uint4*)(Bp + 4096);
        pB2 = *(const uint4*)(Bp + 8192);
        pB3 = *(const uint4*)(Bp + 12288);
    }
    if (32 < K) {
        const unsigned short* Bp = bs.p[0] + (size_t)z * bstride
                                 + (size_t)(32 + bkg * 4) * 4096 + n0 + bn8 * 8;
        qB0 = *(const uint4*)(Bp);
        qB1 = *(const uint4*)(Bp + 4096);
        qB2 = *(const uint4*)(Bp + 8192);
        qB3 = *(const uint4*)(Bp + 12288);
    }

#define KSTEP(KCUR, PB0, PB1, PB2, PB3)                                        \
    {                                                                          \
        __syncthreads();                                                       \
        {                                                                      \
            unsigned short* Ad0 = &As[0][am * APITCH + ahf * 16];              \
            unsigned short* Ad1 = &As[1][am * APITCH + ahf * 16];              \
            ((uint2*)Ad0)[0] = *((const uint2*)&ah0);                          \
            ((uint2*)Ad0)[1] = *((const uint2*)&ah0 + 1);                      \
            ((uint2*)Ad0)[2] = *((const uint2*)&ah1);                          \
            ((uint2*)Ad0)[3] = *((const uint2*)&ah1 + 1);                      \
            ((uint2*)Ad1)[0] = *((const uint2*)&al0);                          \
            ((uint2*)Ad1)[1] = *((const uint2*)&al0 + 1);                      \
            ((uint2*)Ad1)[2] = *((const uint2*)&al1);                          \
            ((uint2*)Ad1)[3] = *((const uint2*)&al1 + 1);                      \
        }                                                                      \
        {                                                                      \
            const unsigned int* d0 = (const unsigned int*)&PB0;                \
            const unsigned int* d1 = (const unsigned int*)&PB1;                \
            const unsigned int* d2 = (const unsigned int*)&PB2;                \
            const unsigned int* d3 = (const unsigned int*)&PB3;                \
            _Pragma("unroll")                                                  \
            for (int i = 0; i < 8; ++i) {                                      \
                unsigned int sel = (i & 1) ? 0x07060302u : 0x05040100u;        \
                uint2 pv;                                                      \
                pv.x = __builtin_amdgcn_perm(d1[i >> 1], d0[i >> 1], sel);     \
                pv.y = __builtin_amdgcn_perm(d3[i >> 1], d2[i >> 1], sel);     \
                *(uint2*)&Bsm[(bn8 * 8 + i) * BPITCH + bkg * 2] = pv;          \
            }                                                                  \
        }                                                                      \
        __syncthreads();                                                       \
        {                                                                      \
            const int kA = (KCUR) + 32;                                        \
            if (kA < K) {                                                      \
                ah0 = *(const uint4*)(Aph + kA);                               \
                ah1 = *(const uint4*)(Aph + kA + 8);                           \
                al0 = *(const uint4*)(Apl + kA);                               \
                al1 = *(const uint4*)(Apl + kA + 8);                           \
            }                                                                  \
            const int kB = (KCUR) + 64;                                        \
            if (kB < K) {                                                      \
                const unsigned short* Bp = bs.p[kB >> 8] + (size_t)z * bstride \
                    + (size_t)((kB & 255) + bkg * 4) * 4096 + n0 + bn8 * 8;    \
                PB0 = *(const uint4*)(Bp);                                     \
                PB1 = *(const uint4*)(Bp + 4096);                              \
                PB2 = *(const uint4*)(Bp + 8192);                              \
                PB3 = *(const uint4*)(Bp + 12288);                             \
            }                                                                  \
        }                                                                      \
        _Pragma("unroll")                                                      \
        for (int s = 0; s < 2; ++s) {                                          \
            union { short8 v; uint2 u[2]; } afh[2], afl[2], bfr[4];            \
            _Pragma("unroll")                                                  \
            for (int i = 0; i < 2; ++i) {                                      \
                int rb = (wm + 32 * i + lm) * APITCH + s * 16 + q * 8;         \
                afh[i].u[0] = *(const uint2*)&As[0][rb];                       \
                afh[i].u[1] = *(const uint2*)&As[0][rb + 4];                   \
                afl[i].u[0] = *(const uint2*)&As[1][rb];                       \
                afl[i].u[1] = *(const uint2*)&As[1][rb + 4];                   \
            }                                                                  \
            _Pragma("unroll")                                                  \
            for (int j = 0; j < 4; ++j) {                                      \
                int nb = (wn + 32 * j + lm) * BPITCH + s * 8 + q * 4;          \
                bfr[j].u[0] = *(const uint2*)&Bsm[nb];                         \
                bfr[j].u[1] = *(const uint2*)&Bsm[nb + 2];                     \
            }                                                                  \
            _Pragma("unroll")                                                  \
            for (int i = 0; i < 2; ++i)                                        \
                _Pragma("unroll")                                              \
                for (int j = 0; j < 4; ++j) {                                  \
                    acc[i][j] = __builtin_amdgcn_mfma_f32_32x32x16_bf16(       \
                        afh[i].v, bfr[j].v, acc[i][j], 0, 0, 0);               \
                    acc[i][j] = __builtin_amdgcn_mfma_f32_32x32x16_bf16(       \
                        afl[i].v, bfr[j].v, acc[i][j], 0, 0, 0);               \
                }                                                              \
        }                                                                      \
    }

    for (int k0 = 0; k0 < K; k0 += 64) {
        KSTEP(k0,      pB0, pB1, pB2, pB3);
        KSTEP(k0 + 32, qB0, qB1, qB2, qB3);
    }
#undef KSTEP

    // ---- epilogue; C/D: col=lane&31, row=(reg&3)+8*(reg>>2)+4*(lane>>5)
#pragma unroll
    for (int i = 0; i < 2; ++i)
#pragma unroll
        for (int j = 0; j < 4; ++j)
#pragma unroll
            for (int r = 0; r < 16; ++r) {
                int row = wm + 32 * i + (r & 3) + 8 * (r >> 2) + 4 * q;
                int col = n0 + wn + 32 * j + lm;
                int mg  = m0 + row;
                size_t ob = ((size_t)z * OC + mg) * 4096 + col;
                float v = acc[i][j][r] + bias[mA + row];
                if (EPI == 0) {
                    ((unsigned short*)outv)[ob] = f2bf(silu_f(v));
                } else if (EPI == 1) {
                    float g = bf2f(gate[((size_t)(b0 + z) * 1024 + mg) * 4096 + col]);
                    ((unsigned short*)outv)[ob] = f2bf(v * g);
                } else {
                    ((float*)outv)[ob] = silu_f(v);
                }
            }
}

// ---------------- fully-fused pool cascades (TMA x3 + RW x3).
// 512 threads/block, one plane/block; lane = column, each thread owns 8 rows
// in registers (v[8] only -- RW restart re-reads x_aux from global, which is
// L2/L3-hot). Horizontal taps via __shfl, vertical via two 16KB LDS transpose
// buffers. Small live state: no scratch spill (round-2 lesson: x0[16]+v[16]
// spilled -> 647MB HBM traffic). Arithmetic identical to passing versions.
__global__ __launch_bounds__(512, 4)
void pool_casc_both(const unsigned short* __restrict__ in,
                    unsigned short* __restrict__ t1, unsigned short* __restrict__ t2,
                    unsigned short* __restrict__ t3, unsigned short* __restrict__ r1,
                    unsigned short* __restrict__ r2, unsigned short* __restrict__ r3)
{
    __shared__ float ha[4096], hb[4096];
    const size_t base = (size_t)blockIdx.x * 4096;
    const int t    = threadIdx.x;
    const int lane = t & 63;       // column
    const int w    = t >> 6;       // wave id 0..7 -> rows w, w+8, ..., w+56

    const int il2 = (lane - 2) & 63, il1 = (lane - 1) & 63;
    const int ir1 = (lane + 1) & 63, ir2 = (lane + 2) & 63;
    const bool vl2 = lane >= 2, vl1 = lane >= 1;
    const bool vr1 = lane <= 62, vr2 = lane <= 61;

    float v[8];
#pragma unroll
    for (int k = 0; k < 8; ++k)
        v[k] = bf2f(in[base + (size_t)(w + 8 * k) * 64 + lane]);

    // ---- TMaxAvg cascade (3 stages)
#pragma unroll
    for (int s = 0; s < 3; ++s) {
        unsigned short* outp = (s == 0) ? t1 : (s == 1) ? t2 : t3;
        // horizontal: shuffles, write (max,sum) to ha/hb
#pragma unroll
        for (int k = 0; k < 8; ++k) {
            float c = v[k];
            float a2 = __shfl(c, il2, 64);
            float a1 = __shfl(c, il1, 64);
            float b1 = __shfl(c, ir1, 64);
            float b2 = __shfl(c, ir2, 64);
            float mx = -INFINITY, sm = 0.0f;
            mx = vl2 ? fmaxf(mx, a2) : mx;  sm = vl2 ? (sm + a2) : sm;
            mx = vl1 ? fmaxf(mx, a1) : mx;  sm = vl1 ? (sm + a1) : sm;
            mx = fmaxf(mx, c);              sm = sm + c;
            mx = vr1 ? fmaxf(mx, b1) : mx;  sm = vr1 ? (sm + b1) : sm;
            mx = vr2 ? fmaxf(mx, b2) : mx;  sm = vr2 ? (sm + b2) : sm;
            int r = w + 8 * k;
            ha[r * 64 + lane] = mx;
            hb[r * 64 + lane] = sm;
        }
        __syncthreads();
        // vertical: 5 taps from ha/hb (2 lanes/bank = free)
#pragma unroll
        for (int k = 0; k < 8; ++k) {
            int r = w + 8 * k;
            float mx = -INFINITY, sm = 0.0f;
#pragma unroll
            for (int dy = -2; dy <= 2; ++dy) {
                int rr = r + dy;
                if (0 <= rr && rr < 64) {
                    mx = fmaxf(mx, ha[rr * 64 + lane]);
                    sm += hb[rr * 64 + lane];
                }
            }
            float res = 0.9f * mx + 0.1f * (sm * (1.0f / 25.0f));
            v[k] = res;
            outp[base + (size_t)r * 64 + lane] = f2bf(res);
        }
        __syncthreads();
    }

    // ---- RW cascade (3 stages); restart from x_aux (L2/L3-hot re-read)
#pragma unroll
    for (int k = 0; k < 8; ++k)
        v[k] = bf2f(in[base + (size_t)(w + 8 * k) * 64 + lane]);
#pragma unroll
    for (int s = 0; s < 3; ++s) {
        unsigned short* outp = (s == 0) ? r1 : (s == 1) ? r2 : r3;
        // horizontal: e computed in-lane; shuffle both e and src
#pragma unroll
        for (int k = 0; k < 8; ++k) {
            float c = v[k];
            float e = expf(c);
            float ea2 = __shfl(e, il2, 64), ca2 = __shfl(c, il2, 64);
            float ea1 = __shfl(e, il1, 64), ca1 = __shfl(c, il1, 64);
            float eb1 = __shfl(e, ir1, 64), cb1 = __shfl(c, ir1, 64);
            float eb2 = __shfl(e, ir2, 64), cb2 = __shfl(c, ir2, 64);
            float se = 0.0f, sx = 0.0f;
            se = vl2 ? (se + ea2) : se;  sx = vl2 ? (sx + ea2 * ca2) : sx;
            se = vl1 ? (se + ea1) : se;  sx = vl1 ? (sx + ea1 * ca1) : sx;
            se = se + e;                 sx = sx + e * c;
            se = vr1 ? (se + eb1) : se;  sx = vr1 ? (sx + eb1 * cb1) : sx;
            se = vr2 ? (se + eb2) : se;  sx = vr2 ? (sx + eb2 * cb2) : sx;
            int r = w + 8 * k;
            ha[r * 64 + lane] = sx;
            hb[r * 64 + lane] = se;
        }
        __syncthreads();
        // vertical
#pragma unroll
        for (int k = 0; k < 8; ++k) {
            int r = w + 8 * k;
            float se = 0.0f, sx = 0.0f;
#pragma unroll
            for (int dy = -2; dy <= 2; ++dy) {
                int rr = r + dy;
                if (0 <= rr && rr < 64) {
                    sx += ha[rr * 64 + lane];
                    se += hb[rr * 64 + lane];
                }
            }
            float res = sx / (se + 1e-6f);
            v[k] = res;
            outp[base + (size_t)r * 64 + lane] = f2bf(res);
        }
        __syncthreads();
    }
}

// ---------------- fused LSKA depthwise chain for a batch-QUAD, bf16 io.
// Same structure as pool_casc_both: 512 threads, one channel-plane/block,
// lane = column, 8 rows/thread in registers. Horizontal convs (k=3, dil 1
// and dil 2) via __shfl +-1/+-2; vertical convs via 16KB LDS transpose
// buffers. fmaf order (center, left, right) identical to previous version.
__global__ __launch_bounds__(512, 4)
void lska_dw_quad(const unsigned short* __restrict__ Y2b, int b0,
                  const float* __restrict__ wh1, const float* __restrict__ bh1,
                  const float* __restrict__ wv1, const float* __restrict__ bv1,
                  const float* __restrict__ wh2, const float* __restrict__ bh2,
                  const float* __restrict__ wv2, const float* __restrict__ bv2,
                  unsigned short* __restrict__ outq)
{
    __shared__ float bufA[4096], bufB[4096];
    const int bi = blockIdx.x;
    const int zz = bi >> 10, c = bi & 1023;
    const unsigned short* src = Y2b + ((size_t)(b0 + zz) * 1024 + c) * 4096;
    unsigned short* dst = outq + (size_t)bi * 4096;
    const int t = threadIdx.x;
    const int lane = t & 63, w = t >> 6;

    const int il1 = (lane - 1) & 63, ir1 = (lane + 1) & 63;
    const int il2 = (lane - 2) & 63, ir2 = (lane + 2) & 63;
    const bool vl1 = lane >= 1, vr1 = lane <= 62;
    const bool vl2 = lane >= 2, vr2 = lane <= 61;

    const float h1w0 = wh1[c * 3], h1w1 = wh1[c * 3 + 1], h1w2 = wh1[c * 3 + 2], h1b = bh1[c];
    const float v1w0 = wv1[c * 3], v1w1 = wv1[c * 3 + 1], v1w2 = wv1[c * 3 + 2], v1b = bv1[c];
    const float h2w0 = wh2[c * 3], h2w1 = wh2[c * 3 + 1], h2w2 = wh2[c * 3 + 2], h2b = bh2[c];
    const float v2w0 = wv2[c * 3], v2w1 = wv2[c * 3 + 1], v2w2 = wv2[c * 3 + 2], v2b = bv2[c];

    float v[8];
#pragma unroll
    for (int k = 0; k < 8; ++k)
        v[k] = bf2f(src[(size_t)(w + 8 * k) * 64 + lane]);

    // H1 (dil 1): shuffles -> bufA
#pragma unroll
    for (int k = 0; k < 8; ++k) {
        float cv = v[k];
        float cl = __shfl(cv, il1, 64);
        float cr = __shfl(cv, ir1, 64);
        float a = fmaf(h1w1, cv, h1b);
        a = vl1 ? fmaf(h1w0, cl, a) : a;
        a = vr1 ? fmaf(h1w2, cr, a) : a;
        bufA[(w + 8 * k) * 64 + lane] = a;
    }
    __syncthreads();
    // V1 (dil 1): LDS taps -> reg
#pragma unroll
    for (int k = 0; k < 8; ++k) {
        int r = w + 8 * k;
        float a = fmaf(v1w1, bufA[r * 64 + lane], v1b);
        if (r >= 1)  a = fmaf(v1w0, bufA[(r - 1) * 64 + lane], a);
        if (r <= 62) a = fmaf(v1w2, bufA[(r + 1) * 64 + lane], a);
        v[k] = a;
    }
    // H2 (dil 2): shuffles -> bufB
#pragma unroll
    for (int k = 0; k < 8; ++k) {
        float cv = v[k];
        float cl = __shfl(cv, il2, 64);
        float cr = __shfl(cv, ir2, 64);
        float a = fmaf(h2w1, cv, h2b);
        a = vl2 ? fmaf(h2w0, cl, a) : a;
        a = vr2 ? fmaf(h2w2, cr, a) : a;
        bufB[(w + 8 * k) * 64 + lane] = a;
    }
    __syncthreads();
    // V2 (dil 2): LDS taps -> out
#pragma unroll
    for (int k = 0; k < 8; ++k) {
        int r = w + 8 * k;
        float a = fmaf(v2w1, bufB[r * 64 + lane], v2b);
        if (r >= 2)  a = fmaf(v2w0, bufB[(r - 2) * 64 + lane], a);
        if (r <= 61) a = fmaf(v2w2, bufB[(r + 2) * 64 + lane], a);
        dst[(size_t)r * 64 + lane] = f2bf(a);
    }
}

// ---------------- conversions
__global__ void f2bf_vec(const float* __restrict__ in, unsigned short* __restrict__ out)
{
    size_t i = ((size_t)blockIdx.x * 256 + threadIdx.x) * 8;
    float4 v0 = *(const float4*)(in + i);
    float4 v1 = *(const float4*)(in + i + 4);
    uint2 o0, o1;
    o0.x = (unsigned)f2bf(v0.x) | ((unsigned)f2bf(v0.y) << 16);
    o0.y = (unsigned)f2bf(v0.z) | ((unsigned)f2bf(v0.w) << 16);
    o1.x = (unsigned)f2bf(v1.x) | ((unsigned)f2bf(v1.y) << 16);
    o1.y = (unsigned)f2bf(v1.z) | ((unsigned)f2bf(v1.w) << 16);
    *(uint2*)(out + i) = o0;
    *(uint2*)(out + i + 4) = o1;
}

// all 5 weight hi/lo splits in one dispatch; blockIdx.y = segment,
// oversized segments exit early (grid.x sized for the largest).
struct WSeg { const float* src; unsigned short* dh; unsigned short* dl; int n; };
struct WTab { WSeg s[5]; };

__global__ void wsplit_all(WTab tab)
{
    const WSeg w = tab.s[blockIdx.y];
    const int i = blockIdx.x * 256 + threadIdx.x;
    if (i >= w.n) return;
    float v = w.src[i];
    unsigned short h = f2bf(v);
    w.dh[i] = h;
    w.dl[i] = f2bf(v - bf2f(h));
}

extern "C" void kernel_launch(void* const* d_in, const int* in_sizes, int n_in,
                              void* d_out, int out_size, void* d_ws, size_t ws_size,
                              hipStream_t stream)
{
    const float* x       = (const float*)d_in[0];
    const float* w_sta   = (const float*)d_in[1];
    const float* b_sta   = (const float*)d_in[2];
    const float* w_cv1   = (const float*)d_in[3];
    const float* b_cv1   = (const float*)d_in[4];
    const float* w_cv2   = (const float*)d_in[5];
    const float* b_cv2   = (const float*)d_in[6];
    const float* w_cvend = (const float*)d_in[7];
    const float* b_cvend = (const float*)d_in[8];
    const float* w_dwh   = (const float*)d_in[9];
    const float* b_dwh   = (const float*)d_in[10];
    const float* w_dwv   = (const float*)d_in[11];
    const float* b_dwv   = (const float*)d_in[12];
    const float* w_ddwh  = (const float*)d_in[13];
    const float* b_ddwh  = (const float*)d_in[14];
    const float* w_ddwv  = (const float*)d_in[15];
    const float* b_ddwv  = (const float*)d_in[16];
    const float* w_c1    = (const float*)d_in[17];
    const float* b_c1    = (const float*)d_in[18];
    float* outf = (float*)d_out;
    unsigned short* Y2b = (unsigned short*)d_out;   // [8,1024,4096] bf16 = 67.1 MB

    // ws (bf16 element offsets), capacity 128 MiB = 67.1M shorts:
    //   phase 1-4: xaux, t1..t3, r1..r3 (7 x 8,388,608 shorts = 117.4 MB)
    //   WT weights hi/lo at +58,720,256 (5,505,024 shorts, ends 64.2M = 128.5 MB)
    // Overlays: xb (input bf16, 16.7M shorts) = t1..t2 (dead until pools run);
    //   phase-5: a4q = xaux+t1 (quad, 16.8M shorts),
    //            gq8 = t2..r2 (BOTH quads, 33.6M shorts, ends 50.3M < WT) --
    //            pools dead then; single cvend over all 8 batches.
    unsigned short* WS   = (unsigned short*)d_ws;
    unsigned short* xaux = WS;
    unsigned short* t1   = WS + 8388608;
    unsigned short* t2   = WS + 16777216;
    unsigned short* t3   = WS + 25165824;
    unsigned short* r1   = WS + 33554432;
    unsigned short* r2   = WS + 41943040;
    unsigned short* r3   = WS + 50331648;
    unsigned short* WT   = WS + 58720256;
    unsigned short* xb   = t1;
    unsigned short* a4q  = WS;
    unsigned short* gq8  = WS + 16777216;

    unsigned short* sta_h = WT,           * sta_l = WT + 131072;
    unsigned short* cv1_h = WT + 262144,  * cv1_l = WT + 786432;
    unsigned short* cv2_h = WT + 1310720, * cv2_l = WT + 1835008;
    unsigned short* c1_h  = WT + 2359296, * c1_l  = WT + 3407872;
    unsigned short* cve_h = WT + 4456448, * cve_l = WT + 4980736;

    dim3 blk(256);

    // 0) conversions (input cast + all weight splits in one dispatch)
    f2bf_vec<<<8192, blk, 0, stream>>>(x, xb);
    {
        WTab tab;
        tab.s[0] = { w_sta,   sta_h, sta_l, 131072  };
        tab.s[1] = { w_cv1,   cv1_h, cv1_l, 524288  };
        tab.s[2] = { w_cv2,   cv2_h, cv2_l, 524288  };
        tab.s[3] = { w_c1,    c1_h,  c1_l,  1048576 };
        tab.s[4] = { w_cvend, cve_h, cve_l, 524288  };
        wsplit_all<<<dim3(4096, 5), blk, 0, stream>>>(tab);
    }

    // 1) x_aux = SiLU(sta(x)) -> bf16 [8,256,4096]
    {
        BSlots s; s.p[0] = xb; s.p[1] = xb + 1048576; s.p[2] = xb; s.p[3] = xb;
        gemm_mfma<0><<<dim3(16, 2, 8), blk, 0, stream>>>(
            sta_h, sta_l, nullptr, nullptr, 512, s, s, 2097152L,
            b_sta, nullptr, xaux, 256, nullptr, 0, 512);
    }

    // 2+3) fused pool cascades: TMA -> t1,t2,t3 and RW -> r1,r2,r3
    //      (t1 overwrites xb, which is dead after the sta GEMM)
    pool_casc_both<<<2048, dim3(512), 0, stream>>>(xaux, t1, t2, t3, r1, r2, r3);

    // 4) merged cv1+cv2 -> Y2b channels [0,512)=cv1, [512,1024)=cv2
    {
        BSlots s1; s1.p[0] = xaux; s1.p[1] = t1; s1.p[2] = t2; s1.p[3] = t3;
        BSlots s2; s2.p[0] = xaux; s2.p[1] = r1; s2.p[2] = r2; s2.p[3] = r3;
        gemm_mfma<0><<<dim3(16, 8, 8), blk, 0, stream>>>(
            cv1_h, cv1_l, cv2_h, cv2_l, 1024, s1, s2, 1048576L,
            b_cv1, b_cv2, Y2b, 1024, nullptr, 0, 1024);
    }

    // 5) per quad: dw chain -> a4q ; gated c1 -> gq8[qd]
    for (int qd = 0; qd < 2; ++qd) {
        const int b0 = 4 * qd;
        lska_dw_quad<<<4096, dim3(512), 0, stream>>>(Y2b, b0,
                                               w_dwh, b_dwh, w_dwv, b_dwv,
                                               w_ddwh, b_ddwh, w_ddwv, b_ddwv, a4q);
        {
            BSlots s; s.p[0] = a4q; s.p[1] = a4q + 1048576;
            s.p[2] = a4q + 2097152; s.p[3] = a4q + 3145728;
            gemm_mfma<1><<<dim3(16, 8, 4), blk, 0, stream>>>(
                c1_h, c1_l, nullptr, nullptr, 1024, s, s, 4194304L,
                b_c1, nullptr, gq8 + (size_t)qd * 16777216, 1024, Y2b, b0, 1024);
        }
    }
    // 6) single cvend over all 8 batches (Y2b dead now) -> d_out f32
    {
        BSlots s; s.p[0] = gq8; s.p[1] = gq8 + 1048576;
        s.p[2] = gq8 + 2097152; s.p[3] = gq8 + 3145728;
        gemm_mfma<2><<<dim3(16, 4, 8), blk, 0, stream>>>(
            cve_h, cve_l, nullptr, nullptr, 1024, s, s, 4194304L,
            b_cvend, nullptr, outf, 512, nullptr, 0, 1024);
    }
}